// Round 3
// baseline (219.849 us; speedup 1.0000x reference)
//
#include <hip/hip_runtime.h>

// ConvSoftArgmax2d: x (8,16,512,512) fp32 -> coords (128,2,256,256), resp (128,1,256,256)
// 3x3 window, stride 2, pad 1. Padding contributes 0 to the pooled exp-sums.
// Each thread computes 4 horizontally-adjacent outputs (wo = 4t..4t+3):
// windows span 9 contiguous columns 8t-1..8t+7 per row -> 1 scalar + 2 float4 loads/row.

#define H  512
#define W  512
#define HO 256
#define WO 256
#define BC 128

struct Acc { float den, numv, gx, gy; };

__device__ __forceinline__ void do_row(const float* __restrict__ row, int t,
                                       float mL, float k, float rs, Acc* a)
{
    float v[9];
    v[0] = row[t ? 8 * t - 1 : 0];                      // col 8t-1 (clamped for t=0)
    float4 q1 = *(const float4*)(row + 8 * t);          // cols 8t..8t+3, 16B aligned
    float4 q2 = *(const float4*)(row + 8 * t + 4);      // cols 8t+4..8t+7, 16B aligned
    v[1] = q1.x; v[2] = q1.y; v[3] = q1.z; v[4] = q1.w;
    v[5] = q2.x; v[6] = q2.y; v[7] = q2.z; v[8] = q2.w;

    float e[9];
#pragma unroll
    for (int i = 0; i < 9; ++i) e[i] = __builtin_amdgcn_exp2f(k * v[i]);
    e[0] *= mL;                                         // mask left col for t=0

#pragma unroll
    for (int j = 0; j < 4; ++j) {
        float e0 = e[2 * j], e1 = e[2 * j + 1], e2 = e[2 * j + 2];
        float rsum = e0 + e1 + e2;
        a[j].den += rsum;
        a[j].gy   = fmaf(rs, rsum, a[j].gy);            // rs const-folded per row
        a[j].gx  += e2 - e0;
        a[j].numv = fmaf(e0, v[2 * j],
                    fmaf(e1, v[2 * j + 1],
                    fmaf(e2, v[2 * j + 2], a[j].numv)));
    }
}

__global__ __launch_bounds__(256) void casm_kernel(
    const float* __restrict__ x, const float* __restrict__ temp,
    float* __restrict__ out)
{
    int idx = blockIdx.x * 256 + threadIdx.x;
    int t  = idx & 63;                 // wo quad: wo = 4t+j, j in 0..3
    int ho = (idx >> 6) & (HO - 1);    // wave-uniform (lane = t)
    int bc = idx >> 14;

    float k = 1.44269504088896340736f / fmaxf(temp[0], 1e-8f);
    float mL = t ? 1.0f : 0.0f;

    const float* __restrict__ xp = x + (size_t)bc * (H * W);
    int r0 = 2 * ho - 1;

    Acc a[4];
#pragma unroll
    for (int j = 0; j < 4; ++j) { a[j].den = 1e-12f; a[j].numv = 0.f; a[j].gx = 0.f; a[j].gy = 0.f; }

    if (r0 >= 0)                                   // wave-uniform branch (ho==0 only)
        do_row(xp + r0 * W,       t, mL, k, -1.0f, a);
    do_row(xp + (r0 + 1) * W,     t, mL, k,  0.0f, a);
    do_row(xp + (r0 + 2) * W,     t, mL, k,  1.0f, a);

    const float scale = 2.0f / 511.0f;
    float4 cx4, cy4, rp4;
    float* cxp = &cx4.x; float* cyp = &cy4.x; float* rpp = &rp4.x;
#pragma unroll
    for (int j = 0; j < 4; ++j) {
        float inv_den = __builtin_amdgcn_rcpf(a[j].den);
        int wo = 4 * t + j;
        cxp[j] = (a[j].gx * inv_den + (float)(2 * wo)) * scale - 1.0f;
        cyp[j] = (a[j].gy * inv_den + (float)(2 * ho)) * scale - 1.0f;
        rpp[j] = a[j].numv * inv_den;
    }

    size_t pix   = (size_t)ho * WO + 4 * t;                 // 16B aligned
    size_t cbase = (size_t)bc * (2 * HO * WO) + pix;
    *(float4*)(out + cbase)            = cx4;               // channel 0: x
    *(float4*)(out + cbase + HO * WO)  = cy4;               // channel 1: y
    *(float4*)(out + (size_t)BC * 2 * HO * WO + (size_t)bc * HO * WO + pix) = rp4;
}

extern "C" void kernel_launch(void* const* d_in, const int* in_sizes, int n_in,
                              void* d_out, int out_size, void* d_ws, size_t ws_size,
                              hipStream_t stream) {
    const float* x    = (const float*)d_in[0];
    const float* temp = (const float*)d_in[1];
    float* out        = (float*)d_out;

    int total  = BC * HO * (WO / 4);    // 2,097,152 threads (4 outputs each)
    int blocks = total / 256;           // 8192
    casm_kernel<<<blocks, 256, 0, stream>>>(x, temp, out);
}